// Round 6
// baseline (648.482 us; speedup 1.0000x reference)
//
#include <hip/hip_runtime.h>
#include <stdint.h>

// RWKV TimeMixing on gfx950. I/O dtype: float32 (per reference).
// R5: 4 launches: prep (wconv+mix3) -> gemm3 (K/V/R fused, grid.z=3)
//     -> wkv_onepass (chained device-scope scan) -> gemmO.
// Fallback if ws_size < 206 MiB: gemm3 split into z=2 + z=1 (5 launches).
// Workspace layout:
//   [0,32M)     bufK bf16 (mix_k)
//   [32M,64M)   bufV bf16 (mix_v)   [fallback: rsig overwrites after KV]
//   [64M,96M)   bufR bf16 (mix_r); rwkv written here after gemm3/gemmR
//   [96M,128M)  kb bf16
//   [128M,136M) wk/wv/wr/wo bf16 (2 MiB each)
//   [136M,140M) scan scratch: snum,sden,smx,flag (1 MiB each)
//   [142M,174M) vb bf16
//   [174M,206M) rsig bf16 (fused path only)

using bf16x8 = __attribute__((ext_vector_type(8))) __bf16;
using f32x4  = __attribute__((ext_vector_type(4))) float;

#define NSER 8192   // B*C series
#define NCHUNK 32
#define CLEN 64     // chunk length; NCHUNK*CLEN == T

union FU { float f; unsigned int u; };

__device__ __forceinline__ unsigned short f2b(float f) {
  FU v; v.f = f;
  unsigned int u = v.u;
  return (unsigned short)((u + 0x7fffu + ((u >> 16) & 1u)) >> 16);
}
__device__ __forceinline__ float b2f(unsigned short h) {
  FU v; v.u = ((unsigned int)h) << 16; return v.f;
}
__device__ __forceinline__ float hi2f(unsigned int packed) {  // high16 as bf16
  FU v; v.u = packed & 0xFFFF0000u; return v.f;
}
__device__ __forceinline__ float lo2f(unsigned int packed) {  // low16 as bf16
  FU v; v.u = packed << 16; return v.f;
}

__device__ __forceinline__ void gl_lds16(const unsigned short* g,
                                         const unsigned short* l) {
  __builtin_amdgcn_global_load_lds(
      (const __attribute__((address_space(1))) void*)g,
      (__attribute__((address_space(3))) void*)l, 16, 0, 0);
}

// ---------------- prep: wconv (blocks 0..4095) + mix3 (blocks 4096..12287) --
__global__ __launch_bounds__(256) void prep_kernel(
    const float* __restrict__ x,
    const float* __restrict__ w0, const float* __restrict__ w1,
    const float* __restrict__ w2, const float* __restrict__ w3,
    unsigned short* __restrict__ o0, unsigned short* __restrict__ o1,
    unsigned short* __restrict__ o2, unsigned short* __restrict__ o3,
    const float* __restrict__ mk, const float* __restrict__ mv,
    const float* __restrict__ mr,
    unsigned short* __restrict__ ok, unsigned short* __restrict__ ov,
    unsigned short* __restrict__ orr, int T, int C)
{
  int bid = blockIdx.x;
  if (bid < 4096) {
    int mat = bid >> 10, blk = bid & 1023;
    const float* src = (mat == 0) ? w0 : (mat == 1) ? w1 : (mat == 2) ? w2 : w3;
    unsigned short* dst = (mat == 0) ? o0 : (mat == 1) ? o1 : (mat == 2) ? o2 : o3;
    int i = blk * 1024 + threadIdx.x * 4;
    float4 v = *(const float4*)(src + i);
    union { int2 i2; unsigned short u[4]; } o;
    o.u[0] = f2b(v.x); o.u[1] = f2b(v.y); o.u[2] = f2b(v.z); o.u[3] = f2b(v.w);
    *(int2*)(dst + i) = o.i2;
    return;
  }
  int i = (bid - 4096) * 256 + threadIdx.x;
  int base = i * 8;
  int row = base / C;          // b*T + t
  int t = row - (row / T) * T; // t within batch
  int c = base - row * C;
  float xv[8], pv[8];
  *(float4*)&xv[0] = *(const float4*)(x + base);
  *(float4*)&xv[4] = *(const float4*)(x + base + 4);
  if (t > 0) {
    *(float4*)&pv[0] = *(const float4*)(x + base - C);
    *(float4*)&pv[4] = *(const float4*)(x + base - C + 4);
  } else {
#pragma unroll
    for (int e = 0; e < 8; ++e) pv[e] = 0.f;
  }
  float mkv[8], mvv[8], mrv[8];
  *(float4*)&mkv[0] = *(const float4*)(mk + c);
  *(float4*)&mkv[4] = *(const float4*)(mk + c + 4);
  *(float4*)&mvv[0] = *(const float4*)(mv + c);
  *(float4*)&mvv[4] = *(const float4*)(mv + c + 4);
  *(float4*)&mrv[0] = *(const float4*)(mr + c);
  *(float4*)&mrv[4] = *(const float4*)(mr + c + 4);
  union { int4 i4; unsigned short u[8]; } a, b2, d;
#pragma unroll
  for (int e = 0; e < 8; ++e) {
    float xe = xv[e], pe = pv[e];
    a.u[e]  = f2b(xe * mkv[e] + pe * (1.f - mkv[e]));
    b2.u[e] = f2b(xe * mvv[e] + pe * (1.f - mvv[e]));
    d.u[e]  = f2b(xe * mrv[e] + pe * (1.f - mrv[e]));
  }
  *(int4*)(ok + base)  = a.i4;
  *(int4*)(ov + base)  = b2.i4;
  *(int4*)(orr + base) = d.i4;
}

// ---------------- GEMM core (m97 structure) ----------------
template<typename EPI>
__device__ __forceinline__ void gemm_core(
    const unsigned short* __restrict__ A,
    const unsigned short* __restrict__ W,
    int mBlk, int nBlk, int N, int K, EPI epi)
{
  __shared__ __align__(16) unsigned short As[128 * 32];
  __shared__ __align__(16) unsigned short Bs[128 * 32];
  const int tid  = threadIdx.x;
  const int lane = tid & 63;
  const int w    = tid >> 6;
  const int wm   = w >> 1, wn = w & 1;
  const int col  = lane & 15, quad = lane >> 4;

  const int s0 = 2 * w, s1 = 2 * w + 1;
  const int rA0 = s0 * 16 + (lane >> 2), rA1 = s1 * 16 + (lane >> 2);
  const int kc  = (lane & 3) * 8;

  const f32x4 zero = {0.f, 0.f, 0.f, 0.f};
  f32x4 acc[4][4];
#pragma unroll
  for (int i = 0; i < 4; ++i)
#pragma unroll
    for (int j = 0; j < 4; ++j) acc[i][j] = zero;

  const unsigned short* Ab = A + (size_t)mBlk * K;
  const unsigned short* Wb = W + (size_t)nBlk * K;
  const unsigned short* gA0 = Ab + (size_t)rA0 * K + kc;
  const unsigned short* gA1 = Ab + (size_t)rA1 * K + kc;
  const unsigned short* gB0 = Wb + (size_t)rA0 * K + kc;
  const unsigned short* gB1 = Wb + (size_t)rA1 * K + kc;
  const unsigned short* lA0 = &As[s0 * 512];
  const unsigned short* lA1 = &As[s1 * 512];
  const unsigned short* lB0 = &Bs[s0 * 512];
  const unsigned short* lB1 = &Bs[s1 * 512];

  for (int k0 = 0; k0 < K; k0 += 32) {
    gl_lds16(gA0 + k0, lA0);
    gl_lds16(gA1 + k0, lA1);
    gl_lds16(gB0 + k0, lB0);
    gl_lds16(gB1 + k0, lB1);
    __syncthreads();

    bf16x8 af[4], bg[4];
#pragma unroll
    for (int i = 0; i < 4; ++i)
      af[i] = *(const bf16x8*)&As[(wm * 64 + i * 16 + col) * 32 + quad * 8];
#pragma unroll
    for (int j = 0; j < 4; ++j)
      bg[j] = *(const bf16x8*)&Bs[(wn * 64 + j * 16 + col) * 32 + quad * 8];
#pragma unroll
    for (int i = 0; i < 4; ++i)
#pragma unroll
      for (int j = 0; j < 4; ++j)
        acc[i][j] = __builtin_amdgcn_mfma_f32_16x16x32_bf16(af[i], bg[j], acc[i][j], 0, 0, 0);

    __syncthreads();
  }

  // epilogue: C/D layout col=lane&15, row=quad*4+reg (m89/m91-verified)
  const int mBase = mBlk + wm * 64, nBase = nBlk + wn * 64;
#pragma unroll
  for (int i = 0; i < 4; ++i)
#pragma unroll
    for (int j = 0; j < 4; ++j)
#pragma unroll
      for (int r = 0; r < 4; ++r)
        epi(mBase + i * 16 + quad * 4 + r, nBase + j * 16 + col, acc[i][j][r]);
}

// fused projection GEMM: logical z = blockIdx.z + zoff
// z=0 -> out0=kb (bf16), z=1 -> out1=vb (bf16), z=2 -> out2=rsig (sigmoid bf16)
__global__ __launch_bounds__(256) void gemm3_kernel(
    const unsigned short* __restrict__ A0, const unsigned short* __restrict__ A1,
    const unsigned short* __restrict__ A2,
    const unsigned short* __restrict__ W0, const unsigned short* __restrict__ W1,
    const unsigned short* __restrict__ W2,
    unsigned short* __restrict__ out0, unsigned short* __restrict__ out1,
    unsigned short* __restrict__ out2, int zoff, int N, int K)
{
  int z = blockIdx.z + zoff;
  const unsigned short* A = (z == 0) ? A0 : (z == 1) ? A1 : A2;
  const unsigned short* W = (z == 0) ? W0 : (z == 1) ? W1 : W2;
  unsigned short* out = (z == 0) ? out0 : (z == 1) ? out1 : out2;
  bool sig = (z == 2);
  gemm_core(A, W, blockIdx.x * 128, blockIdx.y * 128, N, K,
            [&](int rg, int cg, float v) {
              float o = sig ? (1.0f / (1.0f + __expf(-v))) : v;
              out[(size_t)rg * N + cg] = f2b(o);
            });
}

// final GEMM: f32 output
__global__ __launch_bounds__(256) void gemmO_kernel(
    const unsigned short* __restrict__ A, const unsigned short* __restrict__ W,
    float* __restrict__ out, int N, int K)
{
  gemm_core(A, W, blockIdx.x * 128, blockIdx.y * 128, N, K,
            [&](int rg, int cg, float v) {
              out[(size_t)rg * N + cg] = v;
            });
}

// ---------------- WKV single-pass chained scan ----------------
// One thread per (series bc, chunk ch). Local scan of CLEN steps with k,v
// packed in registers; publish inclusive prefix (device scope); spin on
// predecessor; emit outputs. Flag: poisoned 0xAA... != 1 means "not ready".
__global__ __launch_bounds__(256) void wkv_onepass(
    const unsigned short* __restrict__ kb, const unsigned short* __restrict__ vb,
    const unsigned short* __restrict__ rsig,
    const float* __restrict__ td, const float* __restrict__ tf,
    float* __restrict__ snum, float* __restrict__ sden, float* __restrict__ smx,
    int* __restrict__ flag,
    unsigned short* __restrict__ rwkv, int T, int C)
{
  int g = blockIdx.x * 256 + threadIdx.x;   // 0 .. NSER*NCHUNK-1
  int bc = g & (NSER - 1);
  int ch = g >> 13;                          // NSER = 8192 = 2^13
  int c = bc & (C - 1);
  float w = -__expf(td[c]);
  float u = tf[c];
  size_t base = ((size_t)(bc >> 10) * T + (size_t)ch * CLEN) * C + c;

  // load + pack k (hi) | v (lo), CLEN regs
  unsigned int kvq[CLEN];
#pragma unroll
  for (int j = 0; j < CLEN; ++j) {
    size_t a = base + (size_t)j * C;
    kvq[j] = ((unsigned int)kb[a] << 16) | (unsigned int)vb[a];
  }

  // local chunk scan from zero state
  float num = 0.f, den = 0.f, mx = -1e38f;
#pragma unroll
  for (int j = 0; j < CLEN; ++j) {
    float k = hi2f(kvq[j]), v = lo2f(kvq[j]);
    float mw = mx + w;
    float ms = fmaxf(mw, k);
    float s1 = __expf(mw - ms);
    float s2 = __expf(k - ms);
    num = s1 * num + s2 * v;
    den = s1 * den + s2;
    mx = ms;
  }

  // chained inclusive-prefix publication (device scope)
  int idx = ch * NSER + bc;
  float inum, iden, imx;   // incoming state for this chunk
  if (ch == 0) {
    inum = 0.f; iden = 0.f; imx = -1e38f;
    __hip_atomic_store(&snum[idx], num, __ATOMIC_RELAXED, __HIP_MEMORY_SCOPE_AGENT);
    __hip_atomic_store(&sden[idx], den, __ATOMIC_RELAXED, __HIP_MEMORY_SCOPE_AGENT);
    __hip_atomic_store(&smx[idx],  mx,  __ATOMIC_RELAXED, __HIP_MEMORY_SCOPE_AGENT);
    __hip_atomic_store(&flag[idx], 1, __ATOMIC_RELEASE, __HIP_MEMORY_SCOPE_AGENT);
  } else {
    int pidx = idx - NSER;
    while (__hip_atomic_load(&flag[pidx], __ATOMIC_ACQUIRE,
                             __HIP_MEMORY_SCOPE_AGENT) != 1)
      __builtin_amdgcn_s_sleep(8);
    inum = __hip_atomic_load(&snum[pidx], __ATOMIC_RELAXED, __HIP_MEMORY_SCOPE_AGENT);
    iden = __hip_atomic_load(&sden[pidx], __ATOMIC_RELAXED, __HIP_MEMORY_SCOPE_AGENT);
    imx  = __hip_atomic_load(&smx[pidx],  __ATOMIC_RELAXED, __HIP_MEMORY_SCOPE_AGENT);
    // inclusive[ch] = merge(incoming decayed over CLEN steps, local)
    float mi = imx + w * (float)CLEN;
    float mo = fmaxf(mi, mx);
    float e1 = __expf(mi - mo);
    float e2 = __expf(mx - mo);
    float nn = e1 * inum + e2 * num;
    float nd = e1 * iden + e2 * den;
    __hip_atomic_store(&snum[idx], nn, __ATOMIC_RELAXED, __HIP_MEMORY_SCOPE_AGENT);
    __hip_atomic_store(&sden[idx], nd, __ATOMIC_RELAXED, __HIP_MEMORY_SCOPE_AGENT);
    __hip_atomic_store(&smx[idx],  mo, __ATOMIC_RELAXED, __HIP_MEMORY_SCOPE_AGENT);
    __hip_atomic_store(&flag[idx], 1, __ATOMIC_RELEASE, __HIP_MEMORY_SCOPE_AGENT);
  }

  // output phase seeded with incoming state
  num = inum; den = iden; mx = imx;
#pragma unroll 1
  for (int j0 = 0; j0 < CLEN; j0 += 8) {
    float rq[8];
#pragma unroll
    for (int j = 0; j < 8; ++j)
      rq[j] = b2f(rsig[base + (size_t)(j0 + j) * C]);
    // inner: must be fully unrolled wrt kvq index
    switch (j0) {
#define OUT8(J0)                                                           \
      case J0: {                                                           \
        _Pragma("unroll")                                                  \
        for (int j = 0; j < 8; ++j) {                                      \
          float k = hi2f(kvq[J0 + j]), v = lo2f(kvq[J0 + j]);              \
          float ku = k + u;                                                \
          float mo = fmaxf(mx, ku);                                        \
          float e1 = __expf(mx - mo);                                      \
          float e2 = __expf(ku - mo);                                      \
          float o = (e1 * num + e2 * v) / (e1 * den + e2);                 \
          rwkv[base + (size_t)(J0 + j) * C] = f2b(rq[j] * o);              \
          float mw = mx + w;                                               \
          float ms = fmaxf(mw, k);                                         \
          float s1 = __expf(mw - ms);                                      \
          float s2 = __expf(k - ms);                                       \
          num = s1 * num + s2 * v;                                         \
          den = s1 * den + s2;                                             \
          mx = ms;                                                         \
        }                                                                  \
      } break;
      OUT8(0) OUT8(8) OUT8(16) OUT8(24) OUT8(32) OUT8(40) OUT8(48) OUT8(56)
#undef OUT8
    }
  }
}

extern "C" void kernel_launch(void* const* d_in, const int* in_sizes, int n_in,
                              void* d_out, int out_size, void* d_ws, size_t ws_size,
                              hipStream_t stream)
{
  const float* x  = (const float*)d_in[0];
  const float* wk = (const float*)d_in[1];
  const float* wv = (const float*)d_in[2];
  const float* wr = (const float*)d_in[3];
  const float* wo = (const float*)d_in[4];
  const float* td = (const float*)d_in[5];
  const float* tf = (const float*)d_in[6];
  const float* mk = (const float*)d_in[7];
  const float* mv = (const float*)d_in[8];
  const float* mr = (const float*)d_in[9];

  const int B = 8, T = 2048, C = 1024;
  const int M = B * T;      // 16384
  const size_t MB = 1024 * 1024;

  char* ws = (char*)d_ws;
  unsigned short* bufK = (unsigned short*)(ws);              // 32 MiB
  unsigned short* bufV = (unsigned short*)(ws + 32 * MB);    // 32 MiB
  unsigned short* bufR = (unsigned short*)(ws + 64 * MB);    // 32 MiB
  unsigned short* kb   = (unsigned short*)(ws + 96 * MB);    // 32 MiB
  unsigned short* wkb  = (unsigned short*)(ws + 128 * MB);   // 2 MiB each
  unsigned short* wvb  = (unsigned short*)(ws + 130 * MB);
  unsigned short* wrb  = (unsigned short*)(ws + 132 * MB);
  unsigned short* wob  = (unsigned short*)(ws + 134 * MB);
  float* snum = (float*)(ws + 136 * MB);                     // 1 MiB each
  float* sden = (float*)(ws + 137 * MB);
  float* smx  = (float*)(ws + 138 * MB);
  int*   flag = (int*)  (ws + 139 * MB);
  unsigned short* vb   = (unsigned short*)(ws + 142 * MB);   // 32 MiB
  unsigned short* rwkv = bufR;   // dead after projection GEMMs

  const bool fused = (ws_size >= (size_t)206 * MB);
  unsigned short* rsig = fused ? (unsigned short*)(ws + 174 * MB)  // fresh
                               : bufV;  // fallback: written after KV GEMM done

  dim3 gGemm(M / 128, C / 128);

  prep_kernel<<<12288, 256, 0, stream>>>(x, wk, wv, wr, wo, wkb, wvb, wrb, wob,
                                         mk, mv, mr, bufK, bufV, bufR, T, C);
  if (fused) {
    gemm3_kernel<<<dim3(M / 128, C / 128, 3), 256, 0, stream>>>(
        bufK, bufV, bufR, wkb, wvb, wrb, kb, vb, rsig, 0, C, C);
  } else {
    gemm3_kernel<<<dim3(M / 128, C / 128, 2), 256, 0, stream>>>(
        bufK, bufV, bufR, wkb, wvb, wrb, kb, vb, rsig, 0, C, C);
    gemm3_kernel<<<dim3(M / 128, C / 128, 1), 256, 0, stream>>>(
        bufR, bufR, bufR, wrb, wrb, wrb, rsig, rsig, rsig, 2, C, C);
  }
  wkv_onepass<<<(NSER * NCHUNK) / 256, 256, 0, stream>>>(
      kb, vb, rsig, td, tf, snum, sden, smx, flag, rwkv, T, C);
  gemmO_kernel<<<gGemm, 256, 0, stream>>>(rwkv, wob, (float*)d_out, C, C);
}